// Round 14
// baseline (428.729 us; speedup 1.0000x reference)
//
#include <hip/hip_runtime.h>
#include <hip/hip_bf16.h>

#define NEG_SLOPE 0.2f
#define LOG2E 1.44269504088896f

#define NB_SHIFT 9
#define NB_NODES 512      // nodes per bucket
#define NBLK_PART 256     // partition blocks for count/scatter passes
#define DEG_BINS 64       // counting-sort bins for degree-matched pairing

typedef _Float16 half8 __attribute__((ext_vector_type(8)));
typedef _Float16 half4 __attribute__((ext_vector_type(4)));
typedef _Float16 half2t __attribute__((ext_vector_type(2)));

__device__ __forceinline__ void ld4(float* d, const float* p) {
    float4 t = *(const float4*)p;
    d[0] = t.x; d[1] = t.y; d[2] = t.z; d[3] = t.w;
}

__device__ __forceinline__ unsigned pack2h(float a, float b) {
    union { half2t h; unsigned u; } pk;
    pk.h[0] = (_Float16)a; pk.h[1] = (_Float16)b;
    return pk.u;
}

__device__ __forceinline__ half2t u2h2(unsigned u) {
    union { unsigned u; half2t h; } c; c.u = u; return c.h;
}
__device__ __forceinline__ half2t f2h2(float a, float b) {
    half2t r; r[0] = (_Float16)a; r[1] = (_Float16)b; return r;
}

#if __has_builtin(__builtin_amdgcn_perm)
#define PERMB(a, b, s) __builtin_amdgcn_perm((a), (b), (s))
#else
__device__ __forceinline__ unsigned PERMB(unsigned a, unsigned b, unsigned s) {
    unsigned long long v = ((unsigned long long)a << 32) | b;
    unsigned r = 0;
#pragma unroll
    for (int i = 0; i < 4; ++i) {
        unsigned idx = (s >> (8 * i)) & 0xFF;
        r |= ((unsigned)(v >> (8 * idx)) & 0xFF) << (8 * i);
    }
    return r;
}
#endif

#if __has_builtin(__builtin_amdgcn_fdot2)
#define FDOT2(a, b, c) __builtin_amdgcn_fdot2((a), (b), (c), false)
#else
#define FDOT2(a, b, c) fmaf((float)(a)[1], (float)(b)[1], fmaf((float)(a)[0], (float)(b)[0], (c)))
#endif

// full-rate VALU 16-lane-row all-reduce stage (row_ror butterfly, no DS pipe)
#define DPP_ADD(x, ctrl) \
    ((x) + __int_as_float(__builtin_amdgcn_update_dpp(0, __float_as_int(x), (ctrl), 0xf, 0xf, true)))
#define ROW_REDUCE16(x) do { \
    x = DPP_ADD(x, 0x128); \
    x = DPP_ADD(x, 0x124); \
    x = DPP_ADD(x, 0x122); \
    x = DPP_ADD(x, 0x121); \
} while (0)

// one half2 channel-group: z = leaky(xl + xr + ex*wa + ey*wb); logit += z . att
#define CHGRP(xl2, xr2, wa, wb, at2, ex, ey, logit) do { \
    half2t z_ = (xl2) + (xr2); \
    z_ = __builtin_elementwise_fma((ex), (wa), z_); \
    z_ = __builtin_elementwise_fma((ey), (wb), z_); \
    z_ = __builtin_elementwise_max(z_, z_ * NEGS); \
    logit = FDOT2(z_, (at2), logit); \
} while (0)

// ---------------------------------------------------------------------------
// PREP + partA merged: layer-1 transforms -> fp16 PLANAR-CHUNK tables;
// blocks < NBLK_PART also build the per-(bucket,block) edge histogram.
// ---------------------------------------------------------------------------
__global__ void __launch_bounds__(256) prepA_kernel(
    const float* __restrict__ x,
    const float* __restrict__ Wl1, const float* __restrict__ bl1,
    const float* __restrict__ Wr1, const float* __restrict__ br1,
    _Float16* __restrict__ xlh, _Float16* __restrict__ xrh, int N,
    const int* __restrict__ dstv, int* __restrict__ M, int E, int EPB, int NB)
{
    __shared__ int hist[256];
    int blk = blockIdx.x, t = threadIdx.x;
    bool doA = (blk < NBLK_PART);
    if (doA) {
        if (t < NB) hist[t] = 0;
        __syncthreads();
        int s0 = blk * EPB;
        int s1 = min(s0 + EPB, E);
        for (int e = s0 + t; e < s1; e += 256)
            atomicAdd(&hist[((unsigned)dstv[e]) >> NB_SHIFT], 1);
    }

    // prep part (node transforms)
    int gt = blk * 256 + t;
    int n = gt >> 6, tt = gt & 63;
    if (n < N) {
        int h = tt >> 5;
        int cp = tt & 31;
        int c0 = h * 64 + 2 * cp;
        const float* xrow = x + (size_t)n * 6;
        float la = bl1[c0], lb = bl1[c0 + 1];
        float ra = br1[c0], rb = br1[c0 + 1];
#pragma unroll
        for (int f = 0; f < 6; ++f) {
            float xv = xrow[f];
            la = fmaf(xv, Wl1[f * 128 + c0], la);
            lb = fmaf(xv, Wl1[f * 128 + c0 + 1], lb);
            ra = fmaf(xv, Wr1[f * 128 + c0], ra);
            rb = fmaf(xv, Wr1[f * 128 + c0 + 1], rb);
        }
        int pos = (cp >> 1) * 8 + h * 4 + (cp & 1) * 2;
        *(unsigned*)(xlh + (size_t)n * 128 + pos) = pack2h(la, lb);
        *(unsigned*)(xrh + (size_t)n * 128 + pos) = pack2h(ra, rb);
    }

    if (doA) {
        __syncthreads();
        if (t < NB) M[t * NBLK_PART + blk] = hist[t];
    }
}

// ---------------------------------------------------------------------------
// partB1: exclusive scan within each bucket row (across partition blocks).
// ---------------------------------------------------------------------------
__global__ void __launch_bounds__(256) partB1_scanrow(
    int* __restrict__ M, int* __restrict__ btot)
{
    __shared__ int lds[256];
    int bkt = blockIdx.x, t = threadIdx.x;
    int cnt = M[bkt * NBLK_PART + t];
    lds[t] = cnt;
    __syncthreads();
    for (int s = 1; s < 256; s <<= 1) {
        int v = (t >= s) ? lds[t - s] : 0;
        __syncthreads();
        lds[t] += v;
        __syncthreads();
    }
    M[bkt * NBLK_PART + t] = lds[t] - cnt;   // exclusive within row
    if (t == 255) btot[bkt] = lds[255];
}

// ---------------------------------------------------------------------------
// partC: scatter edges into bucket-major intermediate. Bucket prefix computed
// locally from btot. Edge record: .x = src | (dst_local<<23), .y = fp16 ea.
// ---------------------------------------------------------------------------
__global__ void __launch_bounds__(256) partC_scatter(
    const int* __restrict__ srcv, const int* __restrict__ dstv,
    const float2* __restrict__ ea2, const int* __restrict__ M,
    const int* __restrict__ btot,
    int2* __restrict__ ebuf, int E, int EPB, int NB)
{
    __shared__ int pref[256];
    __shared__ int cur[256];
    int blk = blockIdx.x, t = threadIdx.x;
    int v = (t < NB) ? btot[t] : 0;
    pref[t] = v;
    __syncthreads();
    for (int s = 1; s < 256; s <<= 1) {
        int u = (t >= s) ? pref[t - s] : 0;
        __syncthreads();
        pref[t] += u;
        __syncthreads();
    }
    if (t < NB) cur[t] = M[t * NBLK_PART + blk] + (pref[t] - v);
    __syncthreads();
    int s0 = blk * EPB;
    int s1 = min(s0 + EPB, E);
    for (int e = s0 + t; e < s1; e += 256) {
        int d = dstv[e];
        int bkt = ((unsigned)d) >> NB_SHIFT;
        int p = atomicAdd(&cur[bkt], 1);
        float2 ea = ea2[e];
        int2 rec;
        rec.x = srcv[e] | ((d & (NB_NODES - 1)) << 23);
        rec.y = (int)pack2h(ea.x, ea.y);
        ebuf[p] = rec;
    }
}

// ---------------------------------------------------------------------------
// partD: one block per bucket. Per-node histogram + scan -> off; scatter to
// final CSR. Emits degree-sorted RANGE TABLE rng[idx] = (s, e, node, 0) so
// c1/c2 get bounds + node id in ONE 16B load (no perm->off chain).
// ---------------------------------------------------------------------------
__global__ void __launch_bounds__(256) partD_finalize(
    const int2* __restrict__ ebuf, const int* __restrict__ btot,
    int* __restrict__ off, int2* __restrict__ csr_edge,
    int4* __restrict__ rng, int N, int NB, int E)
{
    __shared__ int hist[NB_NODES];
    __shared__ int dg[NB_NODES];
    __shared__ int stt[NB_NODES];
    __shared__ int pref[256];
    __shared__ int cnt[DEG_BINS];
    __shared__ int segv[2];
    int b = blockIdx.x, t = threadIdx.x;
    int v = (t < NB) ? btot[t] : 0;
    pref[t] = v;
    __syncthreads();
    for (int s = 1; s < 256; s <<= 1) {
        int u = (t >= s) ? pref[t - s] : 0;
        __syncthreads();
        pref[t] += u;
        __syncthreads();
    }
    if (t == b) { segv[0] = pref[t] - v; segv[1] = pref[t]; }
    __syncthreads();
    int seg_s = segv[0], seg_e = segv[1];
    int node_base = b << NB_SHIFT;
    int nnodes = min(NB_NODES, N - node_base);
    if (b == 0 && t == 0) off[N] = E;

    for (int i = t; i < NB_NODES; i += 256) hist[i] = 0;
    __syncthreads();
    for (int e = seg_s + t; e < seg_e; e += 256)
        atomicAdd(&hist[((unsigned)ebuf[e].x) >> 23], 1);
    __syncthreads();
    // save degrees before the scan overwrites hist
    for (int i = t; i < NB_NODES; i += 256) dg[i] = hist[i];
    if (t < DEG_BINS) cnt[t] = 0;
    __syncthreads();
    if (t == 0) {
        int run = 0;
        for (int i = 0; i < nnodes; ++i) { int c = hist[i]; hist[i] = run; run += c; }
    }
    __syncthreads();
    // capture start offsets before scatter mutates hist
    for (int i = t; i < nnodes; i += 256) {
        off[node_base + i] = seg_s + hist[i];
        stt[i] = hist[i];
    }
    __syncthreads();
    for (int e = seg_s + t; e < seg_e; e += 256) {
        int2 rec = ebuf[e];
        int dl = ((unsigned)rec.x) >> 23;
        int r = atomicAdd(&hist[dl], 1);
        rec.x &= 0x7FFFFF;                 // strip dst_local -> pure src
        csr_edge[seg_s + r] = rec;
    }

    // degree counting-sort -> range table (per bucket)
    for (int i = t; i < nnodes; i += 256)
        atomicAdd(&cnt[min(dg[i], DEG_BINS - 1)], 1);
    __syncthreads();
    if (t == 0) {
        int run = 0;
        for (int i = 0; i < DEG_BINS; ++i) { int c = cnt[i]; cnt[i] = run; run += c; }
    }
    __syncthreads();
    for (int i = t; i < nnodes; i += 256) {
        int r = atomicAdd(&cnt[min(dg[i], DEG_BINS - 1)], 1);
        int s0 = seg_s + stt[i];
        rng[node_base + r] = make_int4(s0, s0 + dg[i], node_base + i, 0);
    }
}

// ---------------------------------------------------------------------------
// C1: layer-1 aggregation. TWO nodes per wave, degree-matched via the range
// table (ONE 16B load gives bounds + node id). Planar-chunk xlh layout.
// Deep pipeline (edges 2 iters ahead, rows 1 ahead). fp16 pk math.
// ---------------------------------------------------------------------------
__global__ void __launch_bounds__(256) c1_kernel(
    const int4* __restrict__ rng, const int2* __restrict__ csr_edge,
    const _Float16* __restrict__ xlh, const _Float16* __restrict__ xrh,
    const float* __restrict__ We1, const float* __restrict__ att1,
    const float* __restrict__ bias1,
    _Float16* __restrict__ h1h, int N)
{
    int wv = (blockIdx.x * blockDim.x + threadIdx.x) >> 6;
    int lane = threadIdx.x & 63;
    if (2 * wv >= N) return;
    int half = lane >> 5;            // 0: node A, 1: node B
    int idx = 2 * wv + half;
    bool nvalid = (idx < N);
    int4 rv = rng[nvalid ? idx : 0];
    int nc = rv.z;
    int s = rv.x;
    int e = nvalid ? rv.y : rv.x;
    int l = lane & 31;
    int g = l & 15;
    int slot = (l >> 4) & 1;         // 2 slots per half
    unsigned gb = (unsigned)(g << 4);

    const half2t NEGS = f2h2(NEG_SLOPE, NEG_SLOPE);

    // per-lane constants (depend only on g)
    half2t a0h[2], a1h[2], w00h[2], w01h[2], w10h[2], w11h[2];
    {
        float t[4];
        ld4(t, att1 + 4 * g);
        a0h[0] = f2h2(t[0] * LOG2E, t[1] * LOG2E); a0h[1] = f2h2(t[2] * LOG2E, t[3] * LOG2E);
        ld4(t, att1 + 64 + 4 * g);
        a1h[0] = f2h2(t[0] * LOG2E, t[1] * LOG2E); a1h[1] = f2h2(t[2] * LOG2E, t[3] * LOG2E);
        ld4(t, We1 + 4 * g);        w00h[0] = f2h2(t[0], t[1]); w00h[1] = f2h2(t[2], t[3]);
        ld4(t, We1 + 64 + 4 * g);   w01h[0] = f2h2(t[0], t[1]); w01h[1] = f2h2(t[2], t[3]);
        ld4(t, We1 + 128 + 4 * g);  w10h[0] = f2h2(t[0], t[1]); w10h[1] = f2h2(t[2], t[3]);
        ld4(t, We1 + 192 + 4 * g);  w11h[0] = f2h2(t[0], t[1]); w11h[1] = f2h2(t[2], t[3]);
    }

    // xr half2 pairs, planar-chunk layout: direct vector reads
    half2t xr00, xr01, xr10, xr11;
    {
        half8 xrv = *(const half8*)(xrh + (size_t)nc * 128 + 8 * g);
        xr00[0] = xrv[0]; xr00[1] = xrv[1];
        xr01[0] = xrv[2]; xr01[1] = xrv[3];
        xr10[0] = xrv[4]; xr10[1] = xrv[5];
        xr11[0] = xrv[6]; xr11[1] = xrv[7];
    }

    int m = e - s;
    int mo = __shfl_xor(m, 32);
    int iters = (max(m, mo) + 3) >> 2;

    float a0A[4] = {0,0,0,0}, a1A[4] = {0,0,0,0};
    float a0B[4] = {0,0,0,0}, a1B[4] = {0,0,0,0};
    float d0A = 0.f, d1A = 0.f, d0B = 0.f, d1B = 0.f;

    const char* xlb = (const char*)xlh;

    // prologue: edge records for it0, it1; row gathers for it0
    int pA0 = s + slot, pB0 = s + 2 + slot;
    bool vA0 = (pA0 < e), vB0 = (pB0 < e);
    int2 edA0 = csr_edge[vA0 ? pA0 : 0];
    int2 edB0 = csr_edge[vB0 ? pB0 : 0];
    int pA1 = s + 4 + slot, pB1 = s + 6 + slot;
    bool vA1 = (pA1 < e), vB1 = (pB1 < e);
    int2 edA1 = csr_edge[vA1 ? pA1 : 0];
    int2 edB1 = csr_edge[vB1 ? pB1 : 0];
    half8 hvA = *(const half8*)(xlb + (((unsigned)edA0.x) << 8) + gb);
    half8 hvB = *(const half8*)(xlb + (((unsigned)edB0.x) << 8) + gb);

    int p0 = s;
    for (int it = 0; it < iters; ++it, p0 += 4) {
        // prefetch edge records for it+2
        int pA2 = p0 + 8 + slot, pB2 = p0 + 10 + slot;
        bool vA2 = (pA2 < e), vB2 = (pB2 < e);
        int2 edA2 = csr_edge[vA2 ? pA2 : 0];
        int2 edB2 = csr_edge[vB2 ? pB2 : 0];

        // issue row gathers for it+1
        half8 hvAn = *(const half8*)(xlb + (((unsigned)edA1.x) << 8) + gb);
        half8 hvBn = *(const half8*)(xlb + (((unsigned)edB1.x) << 8) + gb);

        unsigned uA = (unsigned)edA0.y, uB = (unsigned)edB0.y;
        half2t exA = u2h2(PERMB(uA, uA, 0x01000100));
        half2t eyA = u2h2(PERMB(uA, uA, 0x03020302));
        half2t exB = u2h2(PERMB(uB, uB, 0x01000100));
        half2t eyB = u2h2(PERMB(uB, uB, 0x03020302));

        // planar-chunk: half2 groups are direct dword views (no perms)
        union { half8 h; unsigned u[4]; } HA, HB;
        HA.h = hvA; HB.h = hvB;
        half2t xA00 = u2h2(HA.u[0]), xA01 = u2h2(HA.u[1]);
        half2t xA10 = u2h2(HA.u[2]), xA11 = u2h2(HA.u[3]);
        half2t xB00 = u2h2(HB.u[0]), xB01 = u2h2(HB.u[1]);
        half2t xB10 = u2h2(HB.u[2]), xB11 = u2h2(HB.u[3]);

        float pA0f = 0.f, pA1f = 0.f, pB0f = 0.f, pB1f = 0.f;
        CHGRP(xA00, xr00, w00h[0], w10h[0], a0h[0], exA, eyA, pA0f);
        CHGRP(xA01, xr01, w00h[1], w10h[1], a0h[1], exA, eyA, pA0f);
        CHGRP(xA10, xr10, w01h[0], w11h[0], a1h[0], exA, eyA, pA1f);
        CHGRP(xA11, xr11, w01h[1], w11h[1], a1h[1], exA, eyA, pA1f);
        CHGRP(xB00, xr00, w00h[0], w10h[0], a0h[0], exB, eyB, pB0f);
        CHGRP(xB01, xr01, w00h[1], w10h[1], a0h[1], exB, eyB, pB0f);
        CHGRP(xB10, xr10, w01h[0], w11h[0], a1h[0], exB, eyB, pB1f);
        CHGRP(xB11, xr11, w01h[1], w11h[1], a1h[1], exB, eyB, pB1f);

        ROW_REDUCE16(pA0f);
        ROW_REDUCE16(pA1f);
        ROW_REDUCE16(pB0f);
        ROW_REDUCE16(pB1f);

        float eA0 = vA0 ? exp2f(pA0f) : 0.f;
        float eA1 = vA0 ? exp2f(pA1f) : 0.f;
        float eB0 = vB0 ? exp2f(pB0f) : 0.f;
        float eB1 = vB0 ? exp2f(pB1f) : 0.f;
        d0A += eA0; d1A += eA1;
        d0B += eB0; d1B += eB1;

        // planar-chunk: head0 = hv[0..3], head1 = hv[4..7]
        a0A[0] = fmaf(eA0, (float)hvA[0], a0A[0]);
        a0A[1] = fmaf(eA0, (float)hvA[1], a0A[1]);
        a0A[2] = fmaf(eA0, (float)hvA[2], a0A[2]);
        a0A[3] = fmaf(eA0, (float)hvA[3], a0A[3]);
        a1A[0] = fmaf(eA1, (float)hvA[4], a1A[0]);
        a1A[1] = fmaf(eA1, (float)hvA[5], a1A[1]);
        a1A[2] = fmaf(eA1, (float)hvA[6], a1A[2]);
        a1A[3] = fmaf(eA1, (float)hvA[7], a1A[3]);
        a0B[0] = fmaf(eB0, (float)hvB[0], a0B[0]);
        a0B[1] = fmaf(eB0, (float)hvB[1], a0B[1]);
        a0B[2] = fmaf(eB0, (float)hvB[2], a0B[2]);
        a0B[3] = fmaf(eB0, (float)hvB[3], a0B[3]);
        a1B[0] = fmaf(eB1, (float)hvB[4], a1B[0]);
        a1B[1] = fmaf(eB1, (float)hvB[5], a1B[1]);
        a1B[2] = fmaf(eB1, (float)hvB[6], a1B[2]);
        a1B[3] = fmaf(eB1, (float)hvB[7], a1B[3]);

        // rotate pipeline
        edA0 = edA1; edB0 = edB1; vA0 = vA1; vB0 = vB1;
        edA1 = edA2; edB1 = edB2; vA1 = vA2; vB1 = vB2;
        hvA = hvAn; hvB = hvBn;
    }

    float acc0[4], acc1[4];
#pragma unroll
    for (int i = 0; i < 4; ++i) { acc0[i] = a0A[i] + a0B[i]; acc1[i] = a1A[i] + a1B[i]; }
    float d0 = d0A + d0B, d1 = d1A + d1B;
#pragma unroll
    for (int i = 0; i < 4; ++i) {
        acc0[i] += __shfl_xor(acc0[i], 16);
        acc1[i] += __shfl_xor(acc1[i], 16);
    }
    d0 += __shfl_xor(d0, 16);
    d1 += __shfl_xor(d1, 16);

    if (slot == 0 && nvalid) {
        float b0[4], b1[4];
        ld4(b0, bias1 + 4 * g);
        ld4(b1, bias1 + 64 + 4 * g);
        float r0 = 1.f / (d0 + 1e-16f), r1 = 1.f / (d1 + 1e-16f);
        half4 o0, o1;
        o0[0] = (_Float16)fmaxf(fmaf(acc0[0], r0, b0[0]), 0.f);
        o0[1] = (_Float16)fmaxf(fmaf(acc0[1], r0, b0[1]), 0.f);
        o0[2] = (_Float16)fmaxf(fmaf(acc0[2], r0, b0[2]), 0.f);
        o0[3] = (_Float16)fmaxf(fmaf(acc0[3], r0, b0[3]), 0.f);
        o1[0] = (_Float16)fmaxf(fmaf(acc1[0], r1, b1[0]), 0.f);
        o1[1] = (_Float16)fmaxf(fmaf(acc1[1], r1, b1[1]), 0.f);
        o1[2] = (_Float16)fmaxf(fmaf(acc1[2], r1, b1[2]), 0.f);
        o1[3] = (_Float16)fmaxf(fmaf(acc1[3], r1, b1[3]), 0.f);
        *(half4*)(h1h + (size_t)nc * 128 + 4 * g) = o0;
        *(half4*)(h1h + (size_t)nc * 128 + 64 + 4 * g) = o1;
    }
}

// ---------------------------------------------------------------------------
// A2: layer-2 node transforms as an LDS-tiled GEMM. h1 read as fp16,
// converted to fp32 during LDS staging. (fp32 math — numerics-safe.)
// ---------------------------------------------------------------------------
__global__ void __launch_bounds__(256) a2_kernel(
    const _Float16* __restrict__ h1h,
    const float* __restrict__ Wl2, const float* __restrict__ bl2,
    const float* __restrict__ Wr2, const float* __restrict__ br2,
    _Float16* __restrict__ xl2h, _Float16* __restrict__ xr2h, int N)
{
    __shared__ float hs[64 * 128];   // 32 KB
    int tid = threadIdx.x;
    int n0 = blockIdx.x * 64;

    for (int i = tid; i < 64 * 16; i += 256) {
        int row = i >> 4;
        int q = i & 15;
        int n = n0 + row;
        float f[8];
        if (n < N) {
            half8 v = *(const half8*)(h1h + (size_t)n * 128 + q * 8);
#pragma unroll
            for (int j = 0; j < 8; ++j) f[j] = (float)v[j];
        } else {
#pragma unroll
            for (int j = 0; j < 8; ++j) f[j] = 0.f;
        }
        *(float4*)(hs + row * 128 + q * 8)     = make_float4(f[0], f[1], f[2], f[3]);
        *(float4*)(hs + row * 128 + q * 8 + 4) = make_float4(f[4], f[5], f[6], f[7]);
    }
    __syncthreads();

    int cslot = tid & 31;
    int jgrp = tid >> 5;
    int c4 = cslot * 4;
    bool isL = (c4 < 64);
    int cc = isL ? c4 : (c4 - 64);
    const float* Wb = (isL ? Wl2 : Wr2) + cc;
    const float* bb = (isL ? bl2 : br2) + cc;
    float4 bias = *(const float4*)bb;

    float acc[8][4];
#pragma unroll
    for (int j = 0; j < 8; ++j) {
        acc[j][0] = bias.x; acc[j][1] = bias.y;
        acc[j][2] = bias.z; acc[j][3] = bias.w;
    }

    const float* hrow = hs + (jgrp * 8) * 128;
#pragma unroll 2
    for (int k4 = 0; k4 < 32; ++k4) {
        float4 w0 = *(const float4*)(Wb + (4 * k4 + 0) * 64);
        float4 w1 = *(const float4*)(Wb + (4 * k4 + 1) * 64);
        float4 w2 = *(const float4*)(Wb + (4 * k4 + 2) * 64);
        float4 w3 = *(const float4*)(Wb + (4 * k4 + 3) * 64);
#pragma unroll
        for (int j = 0; j < 8; ++j) {
            float4 hv = *(const float4*)(hrow + j * 128 + k4 * 4);
            acc[j][0] = fmaf(hv.x, w0.x, acc[j][0]);
            acc[j][1] = fmaf(hv.x, w0.y, acc[j][1]);
            acc[j][2] = fmaf(hv.x, w0.z, acc[j][2]);
            acc[j][3] = fmaf(hv.x, w0.w, acc[j][3]);
            acc[j][0] = fmaf(hv.y, w1.x, acc[j][0]);
            acc[j][1] = fmaf(hv.y, w1.y, acc[j][1]);
            acc[j][2] = fmaf(hv.y, w1.z, acc[j][2]);
            acc[j][3] = fmaf(hv.y, w1.w, acc[j][3]);
            acc[j][0] = fmaf(hv.z, w2.x, acc[j][0]);
            acc[j][1] = fmaf(hv.z, w2.y, acc[j][1]);
            acc[j][2] = fmaf(hv.z, w2.z, acc[j][2]);
            acc[j][3] = fmaf(hv.z, w2.w, acc[j][3]);
            acc[j][0] = fmaf(hv.w, w3.x, acc[j][0]);
            acc[j][1] = fmaf(hv.w, w3.y, acc[j][1]);
            acc[j][2] = fmaf(hv.w, w3.z, acc[j][2]);
            acc[j][3] = fmaf(hv.w, w3.w, acc[j][3]);
        }
    }

    _Float16* outb = isL ? xl2h : xr2h;
#pragma unroll
    for (int j = 0; j < 8; ++j) {
        int n = n0 + jgrp * 8 + j;
        if (n < N) {
            half4 o;
            o[0] = (_Float16)acc[j][0];
            o[1] = (_Float16)acc[j][1];
            o[2] = (_Float16)acc[j][2];
            o[3] = (_Float16)acc[j][3];
            *(half4*)(outb + (size_t)n * 64 + cc) = o;
        }
    }
}

// ---------------------------------------------------------------------------
// C2: layer-2 aggregation. TWO nodes per wave via the range table.
// Writes h2 (N x 64 f32); MLP head in head_kernel.
// ---------------------------------------------------------------------------
__global__ void __launch_bounds__(256) c2_kernel(
    const int4* __restrict__ rng, const int2* __restrict__ csr_edge,
    const _Float16* __restrict__ xl2h, const _Float16* __restrict__ xr2h,
    const float* __restrict__ We2, const float* __restrict__ att2,
    const float* __restrict__ bias2,
    float* __restrict__ h2out, int N)
{
    int wv = (blockIdx.x * blockDim.x + threadIdx.x) >> 6;
    int lane = threadIdx.x & 63;
    if (2 * wv >= N) return;
    int half = lane >> 5;
    int idx = 2 * wv + half;
    bool nvalid = (idx < N);
    int4 rv = rng[nvalid ? idx : 0];
    int nc = rv.z;
    int s = rv.x;
    int e = nvalid ? rv.y : rv.x;
    int l = lane & 31;
    int g = l & 15;
    int slot = (l >> 4) & 1;
    unsigned gb = (unsigned)(g << 3);

    const half2t NEGS = f2h2(NEG_SLOPE, NEG_SLOPE);

    half2t avh[2], w0h[2], w1h[2], xr2[2];
    {
        float t[4];
        ld4(t, att2 + 4 * g);
        avh[0] = f2h2(t[0] * LOG2E, t[1] * LOG2E); avh[1] = f2h2(t[2] * LOG2E, t[3] * LOG2E);
        ld4(t, We2 + 4 * g);       w0h[0] = f2h2(t[0], t[1]); w0h[1] = f2h2(t[2], t[3]);
        ld4(t, We2 + 64 + 4 * g);  w1h[0] = f2h2(t[0], t[1]); w1h[1] = f2h2(t[2], t[3]);
        half4 xh = *(const half4*)(xr2h + (size_t)nc * 64 + 4 * g);
        xr2[0][0] = xh[0]; xr2[0][1] = xh[1];
        xr2[1][0] = xh[2]; xr2[1][1] = xh[3];
    }

    int m = e - s;
    int mo = __shfl_xor(m, 32);
    int iters = (max(m, mo) + 3) >> 2;

    float dA = 0.f, dB = 0.f;
    float aA[4] = {0,0,0,0}, aB[4] = {0,0,0,0};

    const char* xlb = (const char*)xl2h;

    int pA0 = s + slot, pB0 = s + 2 + slot;
    bool vA0 = (pA0 < e), vB0 = (pB0 < e);
    int2 edA0 = csr_edge[vA0 ? pA0 : 0];
    int2 edB0 = csr_edge[vB0 ? pB0 : 0];
    int pA1 = s + 4 + slot, pB1 = s + 6 + slot;
    bool vA1 = (pA1 < e), vB1 = (pB1 < e);
    int2 edA1 = csr_edge[vA1 ? pA1 : 0];
    int2 edB1 = csr_edge[vB1 ? pB1 : 0];
    half4 hvA = *(const half4*)(xlb + (((unsigned)edA0.x) << 7) + gb);
    half4 hvB = *(const half4*)(xlb + (((unsigned)edB0.x) << 7) + gb);

    int p0 = s;
    for (int it = 0; it < iters; ++it, p0 += 4) {
        int pA2 = p0 + 8 + slot, pB2 = p0 + 10 + slot;
        bool vA2 = (pA2 < e), vB2 = (pB2 < e);
        int2 edA2 = csr_edge[vA2 ? pA2 : 0];
        int2 edB2 = csr_edge[vB2 ? pB2 : 0];

        half4 hvAn = *(const half4*)(xlb + (((unsigned)edA1.x) << 7) + gb);
        half4 hvBn = *(const half4*)(xlb + (((unsigned)edB1.x) << 7) + gb);

        unsigned uA = (unsigned)edA0.y, uB = (unsigned)edB0.y;
        half2t exA = u2h2(PERMB(uA, uA, 0x01000100));
        half2t eyA = u2h2(PERMB(uA, uA, 0x03020302));
        half2t exB = u2h2(PERMB(uB, uB, 0x01000100));
        half2t eyB = u2h2(PERMB(uB, uB, 0x03020302));

        union { half4 h; unsigned u[2]; } HA, HB;
        HA.h = hvA; HB.h = hvB;
        half2t xA0 = u2h2(HA.u[0]), xA1 = u2h2(HA.u[1]);
        half2t xB0 = u2h2(HB.u[0]), xB1 = u2h2(HB.u[1]);

        float pA_ = 0.f, pB_ = 0.f;
        CHGRP(xA0, xr2[0], w0h[0], w1h[0], avh[0], exA, eyA, pA_);
        CHGRP(xA1, xr2[1], w0h[1], w1h[1], avh[1], exA, eyA, pA_);
        CHGRP(xB0, xr2[0], w0h[0], w1h[0], avh[0], exB, eyB, pB_);
        CHGRP(xB1, xr2[1], w0h[1], w1h[1], avh[1], exB, eyB, pB_);

        ROW_REDUCE16(pA_);
        ROW_REDUCE16(pB_);
        float evA = vA0 ? exp2f(pA_) : 0.f;
        float evB = vB0 ? exp2f(pB_) : 0.f;
        dA += evA; dB += evB;

        aA[0] = fmaf(evA, (float)hvA[0], aA[0]);
        aA[1] = fmaf(evA, (float)hvA[1], aA[1]);
        aA[2] = fmaf(evA, (float)hvA[2], aA[2]);
        aA[3] = fmaf(evA, (float)hvA[3], aA[3]);
        aB[0] = fmaf(evB, (float)hvB[0], aB[0]);
        aB[1] = fmaf(evB, (float)hvB[1], aB[1]);
        aB[2] = fmaf(evB, (float)hvB[2], aB[2]);
        aB[3] = fmaf(evB, (float)hvB[3], aB[3]);

        edA0 = edA1; edB0 = edB1; vA0 = vA1; vB0 = vB1;
        edA1 = edA2; edB1 = edB2; vA1 = vA2; vB1 = vB2;
        hvA = hvAn; hvB = hvBn;
    }

    float acc[4];
#pragma unroll
    for (int i = 0; i < 4; ++i) acc[i] = aA[i] + aB[i];
    float dsum = dA + dB;
#pragma unroll
    for (int i = 0; i < 4; ++i) acc[i] += __shfl_xor(acc[i], 16);
    dsum += __shfl_xor(dsum, 16);

    if (slot == 0 && nvalid) {
        float b2[4];
        ld4(b2, bias2 + 4 * g);
        float r = 1.f / (dsum + 1e-16f);
        float4 o;
        o.x = fmaxf(fmaf(acc[0], r, b2[0]), 0.f);
        o.y = fmaxf(fmaf(acc[1], r, b2[1]), 0.f);
        o.z = fmaxf(fmaf(acc[2], r, b2[2]), 0.f);
        o.w = fmaxf(fmaf(acc[3], r, b2[3]), 0.f);
        *(float4*)(h2out + (size_t)nc * 64 + 4 * g) = o;
    }
}

// ---------------------------------------------------------------------------
// HEAD: out = relu(h2 @ Wh1 + bh1) @ Wh2 + bh2, tiled GEMM (64 nodes/block).
// ---------------------------------------------------------------------------
__global__ void __launch_bounds__(256) head_kernel(
    const float* __restrict__ h2, const float* __restrict__ Wh1,
    const float* __restrict__ bh1, const float* __restrict__ Wh2,
    const float* __restrict__ bh2, float* __restrict__ out, int N)
{
    __shared__ float hs[64 * 68];   // ~17 KB
    int tid = threadIdx.x;
    int n0 = blockIdx.x * 64;

    for (int i = tid; i < 64 * 16; i += 256) {
        int row = i >> 4, q = i & 15;
        int n = n0 + row;
        float4 v = (n < N) ? *(const float4*)(h2 + (size_t)n * 64 + q * 4)
                           : make_float4(0.f, 0.f, 0.f, 0.f);
        *(float4*)(hs + row * 68 + q * 4) = v;
    }
    __syncthreads();

    int cslot = tid & 15;
    int jgrp  = tid >> 4;
    int c4 = cslot * 4;
    float4 bias = *(const float4*)(bh1 + c4);

    float acc[4][4];
#pragma unroll
    for (int r = 0; r < 4; ++r) {
        acc[r][0] = bias.x; acc[r][1] = bias.y;
        acc[r][2] = bias.z; acc[r][3] = bias.w;
    }

    const float* hrow = hs + (jgrp * 4) * 68;
#pragma unroll 2
    for (int k4 = 0; k4 < 16; ++k4) {
        float4 w0 = *(const float4*)(Wh1 + (4 * k4 + 0) * 64 + c4);
        float4 w1 = *(const float4*)(Wh1 + (4 * k4 + 1) * 64 + c4);
        float4 w2 = *(const float4*)(Wh1 + (4 * k4 + 2) * 64 + c4);
        float4 w3 = *(const float4*)(Wh1 + (4 * k4 + 3) * 64 + c4);
#pragma unroll
        for (int r = 0; r < 4; ++r) {
            float4 hv = *(const float4*)(hrow + r * 68 + k4 * 4);
            acc[r][0] = fmaf(hv.x, w0.x, acc[r][0]);
            acc[r][1] = fmaf(hv.x, w0.y, acc[r][1]);
            acc[r][2] = fmaf(hv.x, w0.z, acc[r][2]);
            acc[r][3] = fmaf(hv.x, w0.w, acc[r][3]);
            acc[r][0] = fmaf(hv.y, w1.x, acc[r][0]);
            acc[r][1] = fmaf(hv.y, w1.y, acc[r][1]);
            acc[r][2] = fmaf(hv.y, w1.z, acc[r][2]);
            acc[r][3] = fmaf(hv.y, w1.w, acc[r][3]);
            acc[r][0] = fmaf(hv.z, w2.x, acc[r][0]);
            acc[r][1] = fmaf(hv.z, w2.y, acc[r][1]);
            acc[r][2] = fmaf(hv.z, w2.z, acc[r][2]);
            acc[r][3] = fmaf(hv.z, w2.w, acc[r][3]);
            acc[r][0] = fmaf(hv.w, w3.x, acc[r][0]);
            acc[r][1] = fmaf(hv.w, w3.y, acc[r][1]);
            acc[r][2] = fmaf(hv.w, w3.z, acc[r][2]);
            acc[r][3] = fmaf(hv.w, w3.w, acc[r][3]);
        }
    }

    float4 w2v = *(const float4*)(Wh2 + c4);
    float p[4];
#pragma unroll
    for (int r = 0; r < 4; ++r) {
        p[r] = fmaxf(acc[r][0], 0.f) * w2v.x
             + fmaxf(acc[r][1], 0.f) * w2v.y
             + fmaxf(acc[r][2], 0.f) * w2v.z
             + fmaxf(acc[r][3], 0.f) * w2v.w;
    }
#pragma unroll
    for (int m = 1; m <= 8; m <<= 1) {
#pragma unroll
        for (int r = 0; r < 4; ++r) p[r] += __shfl_xor(p[r], m);
    }
    if (cslot == 0) {
        float b = bh2[0];
#pragma unroll
        for (int r = 0; r < 4; ++r) {
            int n = n0 + jgrp * 4 + r;
            if (n < N) out[n] = p[r] + b;
        }
    }
}

// ---------------------------------------------------------------------------
extern "C" void kernel_launch(void* const* d_in, const int* in_sizes, int n_in,
                              void* d_out, int out_size, void* d_ws, size_t ws_size,
                              hipStream_t stream) {
    const float* x    = (const float*)d_in[0];
    const int*   ei   = (const int*)d_in[1];
    const float* ea   = (const float*)d_in[2];
    const float* Wl1  = (const float*)d_in[3];
    const float* bl1  = (const float*)d_in[4];
    const float* Wr1  = (const float*)d_in[5];
    const float* br1  = (const float*)d_in[6];
    const float* We1  = (const float*)d_in[7];
    const float* att1 = (const float*)d_in[8];
    const float* bias1= (const float*)d_in[9];
    const float* Wl2  = (const float*)d_in[10];
    const float* bl2  = (const float*)d_in[11];
    const float* Wr2  = (const float*)d_in[12];
    const float* br2  = (const float*)d_in[13];
    const float* We2  = (const float*)d_in[14];
    const float* att2 = (const float*)d_in[15];
    const float* bias2= (const float*)d_in[16];
    const float* Wh1  = (const float*)d_in[17];
    const float* bh1  = (const float*)d_in[18];
    const float* Wh2  = (const float*)d_in[19];
    const float* bh2  = (const float*)d_in[20];

    int N = in_sizes[0] / 6;
    int E = in_sizes[1] / 2;
    const int* srcv = ei;
    const int* dstv = ei + E;

    int NB = (N + NB_NODES - 1) >> NB_SHIFT;
    int EPB = (E + NBLK_PART - 1) / NBLK_PART;

    char* w = (char*)d_ws;
    auto align256 = [](size_t v) { return (v + 255) & ~(size_t)255; };
    _Float16* xlh = (_Float16*)w;
    char* ip = w + align256((size_t)N * 128 * 2);
    _Float16* xrh = (_Float16*)ip; ip += align256((size_t)N * 128 * 2);
    _Float16* h1h = (_Float16*)ip; ip += align256((size_t)N * 128 * 2);
    _Float16* xl2h = (_Float16*)ip; ip += align256((size_t)N * 64 * 2);
    _Float16* xr2h = (_Float16*)ip; ip += align256((size_t)N * 64 * 2);
    int* off = (int*)ip;  ip += align256((size_t)(N + 1) * 4);
    int4* rng = (int4*)ip; ip += align256((size_t)N * 16);
    int* Mbuf = (int*)ip; ip += align256((size_t)NB * NBLK_PART * 4);
    int* btot = (int*)ip; ip += align256((size_t)NB * 4);
    int2* csr_edge = (int2*)ip;

    // ebuf aliases h1h (dead until c1 writes it): E*8 = 12.8MB <= 25.6MB.
    int2* ebuf = (int2*)h1h;
    float* h2 = (float*)xlh;   // h2 aliases xlh (dead after c1)

    int prep_blocks = (int)(((size_t)N * 64 + 255) / 256);
    if (prep_blocks < NBLK_PART) prep_blocks = NBLK_PART;
    prepA_kernel<<<prep_blocks, 256, 0, stream>>>(
        x, Wl1, bl1, Wr1, br1, xlh, xrh, N, dstv, Mbuf, E, EPB, NB);
    partB1_scanrow<<<NB, 256, 0, stream>>>(Mbuf, btot);
    partC_scatter<<<NBLK_PART, 256, 0, stream>>>(
        srcv, dstv, (const float2*)ea, Mbuf, btot, ebuf, E, EPB, NB);
    partD_finalize<<<NB, 256, 0, stream>>>(ebuf, btot, off, csr_edge, rng, N, NB, E);

    size_t nwv = (size_t)((N + 1) / 2);
    c1_kernel<<<(nwv * 64 + 255) / 256, 256, 0, stream>>>(
        rng, csr_edge, xlh, xrh, We1, att1, bias1, h1h, N);
    a2_kernel<<<(N + 63) / 64, 256, 0, stream>>>(
        h1h, Wl2, bl2, Wr2, br2, xl2h, xr2h, N);
    c2_kernel<<<(nwv * 64 + 255) / 256, 256, 0, stream>>>(
        rng, csr_edge, xl2h, xr2h, We2, att2, bias2, h2, N);
    head_kernel<<<(N + 63) / 64, 256, 0, stream>>>(
        h2, Wh1, bh1, Wh2, bh2, (float*)d_out, N);
}

// Round 15
// 421.493 us; speedup vs baseline: 1.0172x; 1.0172x over previous
//
#include <hip/hip_runtime.h>
#include <hip/hip_bf16.h>

#define NEG_SLOPE 0.2f
#define LOG2E 1.44269504088896f

#define NB_SHIFT 9
#define NB_NODES 512      // nodes per bucket
#define NBLK_PART 256     // partition blocks for count/scatter passes
#define DEG_BINS 64       // counting-sort bins for degree-matched pairing

typedef _Float16 half8 __attribute__((ext_vector_type(8)));
typedef _Float16 half4 __attribute__((ext_vector_type(4)));
typedef _Float16 half2t __attribute__((ext_vector_type(2)));

__device__ __forceinline__ void ld4(float* d, const float* p) {
    float4 t = *(const float4*)p;
    d[0] = t.x; d[1] = t.y; d[2] = t.z; d[3] = t.w;
}

__device__ __forceinline__ unsigned pack2h(float a, float b) {
    union { half2t h; unsigned u; } pk;
    pk.h[0] = (_Float16)a; pk.h[1] = (_Float16)b;
    return pk.u;
}

__device__ __forceinline__ half2t u2h2(unsigned u) {
    union { unsigned u; half2t h; } c; c.u = u; return c.h;
}
__device__ __forceinline__ half2t f2h2(float a, float b) {
    half2t r; r[0] = (_Float16)a; r[1] = (_Float16)b; return r;
}

#if __has_builtin(__builtin_amdgcn_perm)
#define PERMB(a, b, s) __builtin_amdgcn_perm((a), (b), (s))
#else
__device__ __forceinline__ unsigned PERMB(unsigned a, unsigned b, unsigned s) {
    unsigned long long v = ((unsigned long long)a << 32) | b;
    unsigned r = 0;
#pragma unroll
    for (int i = 0; i < 4; ++i) {
        unsigned idx = (s >> (8 * i)) & 0xFF;
        r |= ((unsigned)(v >> (8 * idx)) & 0xFF) << (8 * i);
    }
    return r;
}
#endif

#if __has_builtin(__builtin_amdgcn_fdot2)
#define FDOT2(a, b, c) __builtin_amdgcn_fdot2((a), (b), (c), false)
#else
#define FDOT2(a, b, c) fmaf((float)(a)[1], (float)(b)[1], fmaf((float)(a)[0], (float)(b)[0], (c)))
#endif

// full-rate VALU 16-lane-row all-reduce stage (row_ror butterfly, no DS pipe)
#define DPP_ADD(x, ctrl) \
    ((x) + __int_as_float(__builtin_amdgcn_update_dpp(0, __float_as_int(x), (ctrl), 0xf, 0xf, true)))
#define ROW_REDUCE16(x) do { \
    x = DPP_ADD(x, 0x128); \
    x = DPP_ADD(x, 0x124); \
    x = DPP_ADD(x, 0x122); \
    x = DPP_ADD(x, 0x121); \
} while (0)

// one half2 channel-group: z = leaky(xl + xr + ex*wa + ey*wb); logit += z . att
#define CHGRP(xl2, xr2, wa, wb, at2, ex, ey, logit) do { \
    half2t z_ = (xl2) + (xr2); \
    z_ = __builtin_elementwise_fma((ex), (wa), z_); \
    z_ = __builtin_elementwise_fma((ey), (wb), z_); \
    z_ = __builtin_elementwise_max(z_, z_ * NEGS); \
    logit = FDOT2(z_, (at2), logit); \
} while (0)

// ---------------------------------------------------------------------------
// PREP + partA merged: layer-1 transforms -> fp16 PLANAR-CHUNK tables;
// blocks < NBLK_PART also build the per-(bucket,block) edge histogram.
// ---------------------------------------------------------------------------
__global__ void __launch_bounds__(256) prepA_kernel(
    const float* __restrict__ x,
    const float* __restrict__ Wl1, const float* __restrict__ bl1,
    const float* __restrict__ Wr1, const float* __restrict__ br1,
    _Float16* __restrict__ xlh, _Float16* __restrict__ xrh, int N,
    const int* __restrict__ dstv, int* __restrict__ M, int E, int EPB, int NB)
{
    __shared__ int hist[256];
    int blk = blockIdx.x, t = threadIdx.x;
    bool doA = (blk < NBLK_PART);
    if (doA) {
        if (t < NB) hist[t] = 0;
        __syncthreads();
        int s0 = blk * EPB;
        int s1 = min(s0 + EPB, E);
        for (int e = s0 + t; e < s1; e += 256)
            atomicAdd(&hist[((unsigned)dstv[e]) >> NB_SHIFT], 1);
    }

    // prep part (node transforms)
    int gt = blk * 256 + t;
    int n = gt >> 6, tt = gt & 63;
    if (n < N) {
        int h = tt >> 5;
        int cp = tt & 31;
        int c0 = h * 64 + 2 * cp;
        const float* xrow = x + (size_t)n * 6;
        float la = bl1[c0], lb = bl1[c0 + 1];
        float ra = br1[c0], rb = br1[c0 + 1];
#pragma unroll
        for (int f = 0; f < 6; ++f) {
            float xv = xrow[f];
            la = fmaf(xv, Wl1[f * 128 + c0], la);
            lb = fmaf(xv, Wl1[f * 128 + c0 + 1], lb);
            ra = fmaf(xv, Wr1[f * 128 + c0], ra);
            rb = fmaf(xv, Wr1[f * 128 + c0 + 1], rb);
        }
        int pos = (cp >> 1) * 8 + h * 4 + (cp & 1) * 2;
        *(unsigned*)(xlh + (size_t)n * 128 + pos) = pack2h(la, lb);
        *(unsigned*)(xrh + (size_t)n * 128 + pos) = pack2h(ra, rb);
    }

    if (doA) {
        __syncthreads();
        if (t < NB) M[t * NBLK_PART + blk] = hist[t];
    }
}

// ---------------------------------------------------------------------------
// partB1: exclusive scan within each bucket row (across partition blocks).
// ---------------------------------------------------------------------------
__global__ void __launch_bounds__(256) partB1_scanrow(
    int* __restrict__ M, int* __restrict__ btot)
{
    __shared__ int lds[256];
    int bkt = blockIdx.x, t = threadIdx.x;
    int cnt = M[bkt * NBLK_PART + t];
    lds[t] = cnt;
    __syncthreads();
    for (int s = 1; s < 256; s <<= 1) {
        int v = (t >= s) ? lds[t - s] : 0;
        __syncthreads();
        lds[t] += v;
        __syncthreads();
    }
    M[bkt * NBLK_PART + t] = lds[t] - cnt;   // exclusive within row
    if (t == 255) btot[bkt] = lds[255];
}

// ---------------------------------------------------------------------------
// partC: scatter edges into bucket-major intermediate. Bucket prefix computed
// locally from btot. Edge record: .x = src | (dst_local<<23), .y = fp16 ea.
// ---------------------------------------------------------------------------
__global__ void __launch_bounds__(256) partC_scatter(
    const int* __restrict__ srcv, const int* __restrict__ dstv,
    const float2* __restrict__ ea2, const int* __restrict__ M,
    const int* __restrict__ btot,
    int2* __restrict__ ebuf, int E, int EPB, int NB)
{
    __shared__ int pref[256];
    __shared__ int cur[256];
    int blk = blockIdx.x, t = threadIdx.x;
    int v = (t < NB) ? btot[t] : 0;
    pref[t] = v;
    __syncthreads();
    for (int s = 1; s < 256; s <<= 1) {
        int u = (t >= s) ? pref[t - s] : 0;
        __syncthreads();
        pref[t] += u;
        __syncthreads();
    }
    if (t < NB) cur[t] = M[t * NBLK_PART + blk] + (pref[t] - v);
    __syncthreads();
    int s0 = blk * EPB;
    int s1 = min(s0 + EPB, E);
    for (int e = s0 + t; e < s1; e += 256) {
        int d = dstv[e];
        int bkt = ((unsigned)d) >> NB_SHIFT;
        int p = atomicAdd(&cur[bkt], 1);
        float2 ea = ea2[e];
        int2 rec;
        rec.x = srcv[e] | ((d & (NB_NODES - 1)) << 23);
        rec.y = (int)pack2h(ea.x, ea.y);
        ebuf[p] = rec;
    }
}

// ---------------------------------------------------------------------------
// partD: one block per bucket. Per-node histogram + scan -> off; scatter to
// final CSR. Emits degree-sorted RANGE TABLE rng[idx] = (s, e, node, 0)
// (used by c2 only; c1 iterates nodes linearly via off[]).
// ---------------------------------------------------------------------------
__global__ void __launch_bounds__(256) partD_finalize(
    const int2* __restrict__ ebuf, const int* __restrict__ btot,
    int* __restrict__ off, int2* __restrict__ csr_edge,
    int4* __restrict__ rng, int N, int NB, int E)
{
    __shared__ int hist[NB_NODES];
    __shared__ int dg[NB_NODES];
    __shared__ int stt[NB_NODES];
    __shared__ int pref[256];
    __shared__ int cnt[DEG_BINS];
    __shared__ int segv[2];
    int b = blockIdx.x, t = threadIdx.x;
    int v = (t < NB) ? btot[t] : 0;
    pref[t] = v;
    __syncthreads();
    for (int s = 1; s < 256; s <<= 1) {
        int u = (t >= s) ? pref[t - s] : 0;
        __syncthreads();
        pref[t] += u;
        __syncthreads();
    }
    if (t == b) { segv[0] = pref[t] - v; segv[1] = pref[t]; }
    __syncthreads();
    int seg_s = segv[0], seg_e = segv[1];
    int node_base = b << NB_SHIFT;
    int nnodes = min(NB_NODES, N - node_base);
    if (b == 0 && t == 0) off[N] = E;

    for (int i = t; i < NB_NODES; i += 256) hist[i] = 0;
    __syncthreads();
    for (int e = seg_s + t; e < seg_e; e += 256)
        atomicAdd(&hist[((unsigned)ebuf[e].x) >> 23], 1);
    __syncthreads();
    // save degrees before the scan overwrites hist
    for (int i = t; i < NB_NODES; i += 256) dg[i] = hist[i];
    if (t < DEG_BINS) cnt[t] = 0;
    __syncthreads();
    if (t == 0) {
        int run = 0;
        for (int i = 0; i < nnodes; ++i) { int c = hist[i]; hist[i] = run; run += c; }
    }
    __syncthreads();
    // capture start offsets before scatter mutates hist
    for (int i = t; i < nnodes; i += 256) {
        off[node_base + i] = seg_s + hist[i];
        stt[i] = hist[i];
    }
    __syncthreads();
    for (int e = seg_s + t; e < seg_e; e += 256) {
        int2 rec = ebuf[e];
        int dl = ((unsigned)rec.x) >> 23;
        int r = atomicAdd(&hist[dl], 1);
        rec.x &= 0x7FFFFF;                 // strip dst_local -> pure src
        csr_edge[seg_s + r] = rec;
    }

    // degree counting-sort -> range table (per bucket)
    for (int i = t; i < nnodes; i += 256)
        atomicAdd(&cnt[min(dg[i], DEG_BINS - 1)], 1);
    __syncthreads();
    if (t == 0) {
        int run = 0;
        for (int i = 0; i < DEG_BINS; ++i) { int c = cnt[i]; cnt[i] = run; run += c; }
    }
    __syncthreads();
    for (int i = t; i < nnodes; i += 256) {
        int r = atomicAdd(&cnt[min(dg[i], DEG_BINS - 1)], 1);
        int s0 = seg_s + stt[i];
        rng[node_base + r] = make_int4(s0, s0 + dg[i], node_base + i, 0);
    }
}

// ---------------------------------------------------------------------------
// C1: layer-1 aggregation. TWO nodes per wave, LINEAR node order (R11 best:
// sequential xrh/h1h access beats pairing here). Planar-chunk xlh layout.
// Deep pipeline (edges 2 iters ahead, rows 1 ahead). fp16 pk math.
// ---------------------------------------------------------------------------
__global__ void __launch_bounds__(256) c1_kernel(
    const int* __restrict__ off, const int2* __restrict__ csr_edge,
    const _Float16* __restrict__ xlh, const _Float16* __restrict__ xrh,
    const float* __restrict__ We1, const float* __restrict__ att1,
    const float* __restrict__ bias1,
    _Float16* __restrict__ h1h, int N)
{
    int wv = (blockIdx.x * blockDim.x + threadIdx.x) >> 6;
    int lane = threadIdx.x & 63;
    if (2 * wv >= N) return;
    int half = lane >> 5;            // 0: node A, 1: node B
    int n = 2 * wv + half;
    bool nvalid = (n < N);
    int nc = nvalid ? n : 0;
    int l = lane & 31;
    int g = l & 15;
    int slot = (l >> 4) & 1;         // 2 slots per half
    unsigned gb = (unsigned)(g << 4);

    const half2t NEGS = f2h2(NEG_SLOPE, NEG_SLOPE);

    // per-lane constants (depend only on g)
    half2t a0h[2], a1h[2], w00h[2], w01h[2], w10h[2], w11h[2];
    {
        float t[4];
        ld4(t, att1 + 4 * g);
        a0h[0] = f2h2(t[0] * LOG2E, t[1] * LOG2E); a0h[1] = f2h2(t[2] * LOG2E, t[3] * LOG2E);
        ld4(t, att1 + 64 + 4 * g);
        a1h[0] = f2h2(t[0] * LOG2E, t[1] * LOG2E); a1h[1] = f2h2(t[2] * LOG2E, t[3] * LOG2E);
        ld4(t, We1 + 4 * g);        w00h[0] = f2h2(t[0], t[1]); w00h[1] = f2h2(t[2], t[3]);
        ld4(t, We1 + 64 + 4 * g);   w01h[0] = f2h2(t[0], t[1]); w01h[1] = f2h2(t[2], t[3]);
        ld4(t, We1 + 128 + 4 * g);  w10h[0] = f2h2(t[0], t[1]); w10h[1] = f2h2(t[2], t[3]);
        ld4(t, We1 + 192 + 4 * g);  w11h[0] = f2h2(t[0], t[1]); w11h[1] = f2h2(t[2], t[3]);
    }

    // xr half2 pairs, planar-chunk layout: direct vector reads
    half2t xr00, xr01, xr10, xr11;
    {
        half8 xrv = *(const half8*)(xrh + (size_t)nc * 128 + 8 * g);
        xr00[0] = xrv[0]; xr00[1] = xrv[1];
        xr01[0] = xrv[2]; xr01[1] = xrv[3];
        xr10[0] = xrv[4]; xr10[1] = xrv[5];
        xr11[0] = xrv[6]; xr11[1] = xrv[7];
    }

    int s = off[nc];
    int e = nvalid ? off[nc + 1] : s;
    int m = e - s;
    int mo = __shfl_xor(m, 32);
    int iters = (max(m, mo) + 3) >> 2;

    float a0A[4] = {0,0,0,0}, a1A[4] = {0,0,0,0};
    float a0B[4] = {0,0,0,0}, a1B[4] = {0,0,0,0};
    float d0A = 0.f, d1A = 0.f, d0B = 0.f, d1B = 0.f;

    const char* xlb = (const char*)xlh;

    // prologue: edge records for it0, it1; row gathers for it0
    int pA0 = s + slot, pB0 = s + 2 + slot;
    bool vA0 = (pA0 < e), vB0 = (pB0 < e);
    int2 edA0 = csr_edge[vA0 ? pA0 : 0];
    int2 edB0 = csr_edge[vB0 ? pB0 : 0];
    int pA1 = s + 4 + slot, pB1 = s + 6 + slot;
    bool vA1 = (pA1 < e), vB1 = (pB1 < e);
    int2 edA1 = csr_edge[vA1 ? pA1 : 0];
    int2 edB1 = csr_edge[vB1 ? pB1 : 0];
    half8 hvA = *(const half8*)(xlb + (((unsigned)edA0.x) << 8) + gb);
    half8 hvB = *(const half8*)(xlb + (((unsigned)edB0.x) << 8) + gb);

    int p0 = s;
    for (int it = 0; it < iters; ++it, p0 += 4) {
        // prefetch edge records for it+2
        int pA2 = p0 + 8 + slot, pB2 = p0 + 10 + slot;
        bool vA2 = (pA2 < e), vB2 = (pB2 < e);
        int2 edA2 = csr_edge[vA2 ? pA2 : 0];
        int2 edB2 = csr_edge[vB2 ? pB2 : 0];

        // issue row gathers for it+1
        half8 hvAn = *(const half8*)(xlb + (((unsigned)edA1.x) << 8) + gb);
        half8 hvBn = *(const half8*)(xlb + (((unsigned)edB1.x) << 8) + gb);

        unsigned uA = (unsigned)edA0.y, uB = (unsigned)edB0.y;
        half2t exA = u2h2(PERMB(uA, uA, 0x01000100));
        half2t eyA = u2h2(PERMB(uA, uA, 0x03020302));
        half2t exB = u2h2(PERMB(uB, uB, 0x01000100));
        half2t eyB = u2h2(PERMB(uB, uB, 0x03020302));

        // planar-chunk: half2 groups are direct dword views (no perms)
        union { half8 h; unsigned u[4]; } HA, HB;
        HA.h = hvA; HB.h = hvB;
        half2t xA00 = u2h2(HA.u[0]), xA01 = u2h2(HA.u[1]);
        half2t xA10 = u2h2(HA.u[2]), xA11 = u2h2(HA.u[3]);
        half2t xB00 = u2h2(HB.u[0]), xB01 = u2h2(HB.u[1]);
        half2t xB10 = u2h2(HB.u[2]), xB11 = u2h2(HB.u[3]);

        float pA0f = 0.f, pA1f = 0.f, pB0f = 0.f, pB1f = 0.f;
        CHGRP(xA00, xr00, w00h[0], w10h[0], a0h[0], exA, eyA, pA0f);
        CHGRP(xA01, xr01, w00h[1], w10h[1], a0h[1], exA, eyA, pA0f);
        CHGRP(xA10, xr10, w01h[0], w11h[0], a1h[0], exA, eyA, pA1f);
        CHGRP(xA11, xr11, w01h[1], w11h[1], a1h[1], exA, eyA, pA1f);
        CHGRP(xB00, xr00, w00h[0], w10h[0], a0h[0], exB, eyB, pB0f);
        CHGRP(xB01, xr01, w00h[1], w10h[1], a0h[1], exB, eyB, pB0f);
        CHGRP(xB10, xr10, w01h[0], w11h[0], a1h[0], exB, eyB, pB1f);
        CHGRP(xB11, xr11, w01h[1], w11h[1], a1h[1], exB, eyB, pB1f);

        ROW_REDUCE16(pA0f);
        ROW_REDUCE16(pA1f);
        ROW_REDUCE16(pB0f);
        ROW_REDUCE16(pB1f);

        float eA0 = vA0 ? exp2f(pA0f) : 0.f;
        float eA1 = vA0 ? exp2f(pA1f) : 0.f;
        float eB0 = vB0 ? exp2f(pB0f) : 0.f;
        float eB1 = vB0 ? exp2f(pB1f) : 0.f;
        d0A += eA0; d1A += eA1;
        d0B += eB0; d1B += eB1;

        // planar-chunk: head0 = hv[0..3], head1 = hv[4..7]
        a0A[0] = fmaf(eA0, (float)hvA[0], a0A[0]);
        a0A[1] = fmaf(eA0, (float)hvA[1], a0A[1]);
        a0A[2] = fmaf(eA0, (float)hvA[2], a0A[2]);
        a0A[3] = fmaf(eA0, (float)hvA[3], a0A[3]);
        a1A[0] = fmaf(eA1, (float)hvA[4], a1A[0]);
        a1A[1] = fmaf(eA1, (float)hvA[5], a1A[1]);
        a1A[2] = fmaf(eA1, (float)hvA[6], a1A[2]);
        a1A[3] = fmaf(eA1, (float)hvA[7], a1A[3]);
        a0B[0] = fmaf(eB0, (float)hvB[0], a0B[0]);
        a0B[1] = fmaf(eB0, (float)hvB[1], a0B[1]);
        a0B[2] = fmaf(eB0, (float)hvB[2], a0B[2]);
        a0B[3] = fmaf(eB0, (float)hvB[3], a0B[3]);
        a1B[0] = fmaf(eB1, (float)hvB[4], a1B[0]);
        a1B[1] = fmaf(eB1, (float)hvB[5], a1B[1]);
        a1B[2] = fmaf(eB1, (float)hvB[6], a1B[2]);
        a1B[3] = fmaf(eB1, (float)hvB[7], a1B[3]);

        // rotate pipeline
        edA0 = edA1; edB0 = edB1; vA0 = vA1; vB0 = vB1;
        edA1 = edA2; edB1 = edB2; vA1 = vA2; vB1 = vB2;
        hvA = hvAn; hvB = hvBn;
    }

    float acc0[4], acc1[4];
#pragma unroll
    for (int i = 0; i < 4; ++i) { acc0[i] = a0A[i] + a0B[i]; acc1[i] = a1A[i] + a1B[i]; }
    float d0 = d0A + d0B, d1 = d1A + d1B;
#pragma unroll
    for (int i = 0; i < 4; ++i) {
        acc0[i] += __shfl_xor(acc0[i], 16);
        acc1[i] += __shfl_xor(acc1[i], 16);
    }
    d0 += __shfl_xor(d0, 16);
    d1 += __shfl_xor(d1, 16);

    if (slot == 0 && nvalid) {
        float b0[4], b1[4];
        ld4(b0, bias1 + 4 * g);
        ld4(b1, bias1 + 64 + 4 * g);
        float r0 = 1.f / (d0 + 1e-16f), r1 = 1.f / (d1 + 1e-16f);
        half4 o0, o1;
        o0[0] = (_Float16)fmaxf(fmaf(acc0[0], r0, b0[0]), 0.f);
        o0[1] = (_Float16)fmaxf(fmaf(acc0[1], r0, b0[1]), 0.f);
        o0[2] = (_Float16)fmaxf(fmaf(acc0[2], r0, b0[2]), 0.f);
        o0[3] = (_Float16)fmaxf(fmaf(acc0[3], r0, b0[3]), 0.f);
        o1[0] = (_Float16)fmaxf(fmaf(acc1[0], r1, b1[0]), 0.f);
        o1[1] = (_Float16)fmaxf(fmaf(acc1[1], r1, b1[1]), 0.f);
        o1[2] = (_Float16)fmaxf(fmaf(acc1[2], r1, b1[2]), 0.f);
        o1[3] = (_Float16)fmaxf(fmaf(acc1[3], r1, b1[3]), 0.f);
        *(half4*)(h1h + (size_t)n * 128 + 4 * g) = o0;
        *(half4*)(h1h + (size_t)n * 128 + 64 + 4 * g) = o1;
    }
}

// ---------------------------------------------------------------------------
// A2: layer-2 node transforms as an LDS-tiled GEMM. h1 read as fp16,
// converted to fp32 during LDS staging. (fp32 math — numerics-safe.)
// ---------------------------------------------------------------------------
__global__ void __launch_bounds__(256) a2_kernel(
    const _Float16* __restrict__ h1h,
    const float* __restrict__ Wl2, const float* __restrict__ bl2,
    const float* __restrict__ Wr2, const float* __restrict__ br2,
    _Float16* __restrict__ xl2h, _Float16* __restrict__ xr2h, int N)
{
    __shared__ float hs[64 * 128];   // 32 KB
    int tid = threadIdx.x;
    int n0 = blockIdx.x * 64;

    for (int i = tid; i < 64 * 16; i += 256) {
        int row = i >> 4;
        int q = i & 15;
        int n = n0 + row;
        float f[8];
        if (n < N) {
            half8 v = *(const half8*)(h1h + (size_t)n * 128 + q * 8);
#pragma unroll
            for (int j = 0; j < 8; ++j) f[j] = (float)v[j];
        } else {
#pragma unroll
            for (int j = 0; j < 8; ++j) f[j] = 0.f;
        }
        *(float4*)(hs + row * 128 + q * 8)     = make_float4(f[0], f[1], f[2], f[3]);
        *(float4*)(hs + row * 128 + q * 8 + 4) = make_float4(f[4], f[5], f[6], f[7]);
    }
    __syncthreads();

    int cslot = tid & 31;
    int jgrp = tid >> 5;
    int c4 = cslot * 4;
    bool isL = (c4 < 64);
    int cc = isL ? c4 : (c4 - 64);
    const float* Wb = (isL ? Wl2 : Wr2) + cc;
    const float* bb = (isL ? bl2 : br2) + cc;
    float4 bias = *(const float4*)bb;

    float acc[8][4];
#pragma unroll
    for (int j = 0; j < 8; ++j) {
        acc[j][0] = bias.x; acc[j][1] = bias.y;
        acc[j][2] = bias.z; acc[j][3] = bias.w;
    }

    const float* hrow = hs + (jgrp * 8) * 128;
#pragma unroll 2
    for (int k4 = 0; k4 < 32; ++k4) {
        float4 w0 = *(const float4*)(Wb + (4 * k4 + 0) * 64);
        float4 w1 = *(const float4*)(Wb + (4 * k4 + 1) * 64);
        float4 w2 = *(const float4*)(Wb + (4 * k4 + 2) * 64);
        float4 w3 = *(const float4*)(Wb + (4 * k4 + 3) * 64);
#pragma unroll
        for (int j = 0; j < 8; ++j) {
            float4 hv = *(const float4*)(hrow + j * 128 + k4 * 4);
            acc[j][0] = fmaf(hv.x, w0.x, acc[j][0]);
            acc[j][1] = fmaf(hv.x, w0.y, acc[j][1]);
            acc[j][2] = fmaf(hv.x, w0.z, acc[j][2]);
            acc[j][3] = fmaf(hv.x, w0.w, acc[j][3]);
            acc[j][0] = fmaf(hv.y, w1.x, acc[j][0]);
            acc[j][1] = fmaf(hv.y, w1.y, acc[j][1]);
            acc[j][2] = fmaf(hv.y, w1.z, acc[j][2]);
            acc[j][3] = fmaf(hv.y, w1.w, acc[j][3]);
            acc[j][0] = fmaf(hv.z, w2.x, acc[j][0]);
            acc[j][1] = fmaf(hv.z, w2.y, acc[j][1]);
            acc[j][2] = fmaf(hv.z, w2.z, acc[j][2]);
            acc[j][3] = fmaf(hv.z, w2.w, acc[j][3]);
            acc[j][0] = fmaf(hv.w, w3.x, acc[j][0]);
            acc[j][1] = fmaf(hv.w, w3.y, acc[j][1]);
            acc[j][2] = fmaf(hv.w, w3.z, acc[j][2]);
            acc[j][3] = fmaf(hv.w, w3.w, acc[j][3]);
        }
    }

    _Float16* outb = isL ? xl2h : xr2h;
#pragma unroll
    for (int j = 0; j < 8; ++j) {
        int n = n0 + jgrp * 8 + j;
        if (n < N) {
            half4 o;
            o[0] = (_Float16)acc[j][0];
            o[1] = (_Float16)acc[j][1];
            o[2] = (_Float16)acc[j][2];
            o[3] = (_Float16)acc[j][3];
            *(half4*)(outb + (size_t)n * 64 + cc) = o;
        }
    }
}

// ---------------------------------------------------------------------------
// C2: layer-2 aggregation. TWO nodes per wave, degree-matched via the range
// table (pairing is net-positive here: 128B rows halve the locality cost).
// Writes h2 (N x 64 f32); MLP head in head_kernel.
// ---------------------------------------------------------------------------
__global__ void __launch_bounds__(256) c2_kernel(
    const int4* __restrict__ rng, const int2* __restrict__ csr_edge,
    const _Float16* __restrict__ xl2h, const _Float16* __restrict__ xr2h,
    const float* __restrict__ We2, const float* __restrict__ att2,
    const float* __restrict__ bias2,
    float* __restrict__ h2out, int N)
{
    int wv = (blockIdx.x * blockDim.x + threadIdx.x) >> 6;
    int lane = threadIdx.x & 63;
    if (2 * wv >= N) return;
    int half = lane >> 5;
    int idx = 2 * wv + half;
    bool nvalid = (idx < N);
    int4 rv = rng[nvalid ? idx : 0];
    int nc = rv.z;
    int s = rv.x;
    int e = nvalid ? rv.y : rv.x;
    int l = lane & 31;
    int g = l & 15;
    int slot = (l >> 4) & 1;
    unsigned gb = (unsigned)(g << 3);

    const half2t NEGS = f2h2(NEG_SLOPE, NEG_SLOPE);

    half2t avh[2], w0h[2], w1h[2], xr2[2];
    {
        float t[4];
        ld4(t, att2 + 4 * g);
        avh[0] = f2h2(t[0] * LOG2E, t[1] * LOG2E); avh[1] = f2h2(t[2] * LOG2E, t[3] * LOG2E);
        ld4(t, We2 + 4 * g);       w0h[0] = f2h2(t[0], t[1]); w0h[1] = f2h2(t[2], t[3]);
        ld4(t, We2 + 64 + 4 * g);  w1h[0] = f2h2(t[0], t[1]); w1h[1] = f2h2(t[2], t[3]);
        half4 xh = *(const half4*)(xr2h + (size_t)nc * 64 + 4 * g);
        xr2[0][0] = xh[0]; xr2[0][1] = xh[1];
        xr2[1][0] = xh[2]; xr2[1][1] = xh[3];
    }

    int m = e - s;
    int mo = __shfl_xor(m, 32);
    int iters = (max(m, mo) + 3) >> 2;

    float dA = 0.f, dB = 0.f;
    float aA[4] = {0,0,0,0}, aB[4] = {0,0,0,0};

    const char* xlb = (const char*)xl2h;

    int pA0 = s + slot, pB0 = s + 2 + slot;
    bool vA0 = (pA0 < e), vB0 = (pB0 < e);
    int2 edA0 = csr_edge[vA0 ? pA0 : 0];
    int2 edB0 = csr_edge[vB0 ? pB0 : 0];
    int pA1 = s + 4 + slot, pB1 = s + 6 + slot;
    bool vA1 = (pA1 < e), vB1 = (pB1 < e);
    int2 edA1 = csr_edge[vA1 ? pA1 : 0];
    int2 edB1 = csr_edge[vB1 ? pB1 : 0];
    half4 hvA = *(const half4*)(xlb + (((unsigned)edA0.x) << 7) + gb);
    half4 hvB = *(const half4*)(xlb + (((unsigned)edB0.x) << 7) + gb);

    int p0 = s;
    for (int it = 0; it < iters; ++it, p0 += 4) {
        int pA2 = p0 + 8 + slot, pB2 = p0 + 10 + slot;
        bool vA2 = (pA2 < e), vB2 = (pB2 < e);
        int2 edA2 = csr_edge[vA2 ? pA2 : 0];
        int2 edB2 = csr_edge[vB2 ? pB2 : 0];

        half4 hvAn = *(const half4*)(xlb + (((unsigned)edA1.x) << 7) + gb);
        half4 hvBn = *(const half4*)(xlb + (((unsigned)edB1.x) << 7) + gb);

        unsigned uA = (unsigned)edA0.y, uB = (unsigned)edB0.y;
        half2t exA = u2h2(PERMB(uA, uA, 0x01000100));
        half2t eyA = u2h2(PERMB(uA, uA, 0x03020302));
        half2t exB = u2h2(PERMB(uB, uB, 0x01000100));
        half2t eyB = u2h2(PERMB(uB, uB, 0x03020302));

        union { half4 h; unsigned u[2]; } HA, HB;
        HA.h = hvA; HB.h = hvB;
        half2t xA0 = u2h2(HA.u[0]), xA1 = u2h2(HA.u[1]);
        half2t xB0 = u2h2(HB.u[0]), xB1 = u2h2(HB.u[1]);

        float pA_ = 0.f, pB_ = 0.f;
        CHGRP(xA0, xr2[0], w0h[0], w1h[0], avh[0], exA, eyA, pA_);
        CHGRP(xA1, xr2[1], w0h[1], w1h[1], avh[1], exA, eyA, pA_);
        CHGRP(xB0, xr2[0], w0h[0], w1h[0], avh[0], exB, eyB, pB_);
        CHGRP(xB1, xr2[1], w0h[1], w1h[1], avh[1], exB, eyB, pB_);

        ROW_REDUCE16(pA_);
        ROW_REDUCE16(pB_);
        float evA = vA0 ? exp2f(pA_) : 0.f;
        float evB = vB0 ? exp2f(pB_) : 0.f;
        dA += evA; dB += evB;

        aA[0] = fmaf(evA, (float)hvA[0], aA[0]);
        aA[1] = fmaf(evA, (float)hvA[1], aA[1]);
        aA[2] = fmaf(evA, (float)hvA[2], aA[2]);
        aA[3] = fmaf(evA, (float)hvA[3], aA[3]);
        aB[0] = fmaf(evB, (float)hvB[0], aB[0]);
        aB[1] = fmaf(evB, (float)hvB[1], aB[1]);
        aB[2] = fmaf(evB, (float)hvB[2], aB[2]);
        aB[3] = fmaf(evB, (float)hvB[3], aB[3]);

        edA0 = edA1; edB0 = edB1; vA0 = vA1; vB0 = vB1;
        edA1 = edA2; edB1 = edB2; vA1 = vA2; vB1 = vB2;
        hvA = hvAn; hvB = hvBn;
    }

    float acc[4];
#pragma unroll
    for (int i = 0; i < 4; ++i) acc[i] = aA[i] + aB[i];
    float dsum = dA + dB;
#pragma unroll
    for (int i = 0; i < 4; ++i) acc[i] += __shfl_xor(acc[i], 16);
    dsum += __shfl_xor(dsum, 16);

    if (slot == 0 && nvalid) {
        float b2[4];
        ld4(b2, bias2 + 4 * g);
        float r = 1.f / (dsum + 1e-16f);
        float4 o;
        o.x = fmaxf(fmaf(acc[0], r, b2[0]), 0.f);
        o.y = fmaxf(fmaf(acc[1], r, b2[1]), 0.f);
        o.z = fmaxf(fmaf(acc[2], r, b2[2]), 0.f);
        o.w = fmaxf(fmaf(acc[3], r, b2[3]), 0.f);
        *(float4*)(h2out + (size_t)nc * 64 + 4 * g) = o;
    }
}

// ---------------------------------------------------------------------------
// HEAD: out = relu(h2 @ Wh1 + bh1) @ Wh2 + bh2, tiled GEMM (64 nodes/block).
// ---------------------------------------------------------------------------
__global__ void __launch_bounds__(256) head_kernel(
    const float* __restrict__ h2, const float* __restrict__ Wh1,
    const float* __restrict__ bh1, const float* __restrict__ Wh2,
    const float* __restrict__ bh2, float* __restrict__ out, int N)
{
    __shared__ float hs[64 * 68];   // ~17 KB
    int tid = threadIdx.x;
    int n0 = blockIdx.x * 64;

    for (int i = tid; i < 64 * 16; i += 256) {
        int row = i >> 4, q = i & 15;
        int n = n0 + row;
        float4 v = (n < N) ? *(const float4*)(h2 + (size_t)n * 64 + q * 4)
                           : make_float4(0.f, 0.f, 0.f, 0.f);
        *(float4*)(hs + row * 68 + q * 4) = v;
    }
    __syncthreads();

    int cslot = tid & 15;
    int jgrp  = tid >> 4;
    int c4 = cslot * 4;
    float4 bias = *(const float4*)(bh1 + c4);

    float acc[4][4];
#pragma unroll
    for (int r = 0; r < 4; ++r) {
        acc[r][0] = bias.x; acc[r][1] = bias.y;
        acc[r][2] = bias.z; acc[r][3] = bias.w;
    }

    const float* hrow = hs + (jgrp * 4) * 68;
#pragma unroll 2
    for (int k4 = 0; k4 < 16; ++k4) {
        float4 w0 = *(const float4*)(Wh1 + (4 * k4 + 0) * 64 + c4);
        float4 w1 = *(const float4*)(Wh1 + (4 * k4 + 1) * 64 + c4);
        float4 w2 = *(const float4*)(Wh1 + (4 * k4 + 2) * 64 + c4);
        float4 w3 = *(const float4*)(Wh1 + (4 * k4 + 3) * 64 + c4);
#pragma unroll
        for (int r = 0; r < 4; ++r) {
            float4 hv = *(const float4*)(hrow + r * 68 + k4 * 4);
            acc[r][0] = fmaf(hv.x, w0.x, acc[r][0]);
            acc[r][1] = fmaf(hv.x, w0.y, acc[r][1]);
            acc[r][2] = fmaf(hv.x, w0.z, acc[r][2]);
            acc[r][3] = fmaf(hv.x, w0.w, acc[r][3]);
            acc[r][0] = fmaf(hv.y, w1.x, acc[r][0]);
            acc[r][1] = fmaf(hv.y, w1.y, acc[r][1]);
            acc[r][2] = fmaf(hv.y, w1.z, acc[r][2]);
            acc[r][3] = fmaf(hv.y, w1.w, acc[r][3]);
            acc[r][0] = fmaf(hv.z, w2.x, acc[r][0]);
            acc[r][1] = fmaf(hv.z, w2.y, acc[r][1]);
            acc[r][2] = fmaf(hv.z, w2.z, acc[r][2]);
            acc[r][3] = fmaf(hv.z, w2.w, acc[r][3]);
            acc[r][0] = fmaf(hv.w, w3.x, acc[r][0]);
            acc[r][1] = fmaf(hv.w, w3.y, acc[r][1]);
            acc[r][2] = fmaf(hv.w, w3.z, acc[r][2]);
            acc[r][3] = fmaf(hv.w, w3.w, acc[r][3]);
        }
    }

    float4 w2v = *(const float4*)(Wh2 + c4);
    float p[4];
#pragma unroll
    for (int r = 0; r < 4; ++r) {
        p[r] = fmaxf(acc[r][0], 0.f) * w2v.x
             + fmaxf(acc[r][1], 0.f) * w2v.y
             + fmaxf(acc[r][2], 0.f) * w2v.z
             + fmaxf(acc[r][3], 0.f) * w2v.w;
    }
#pragma unroll
    for (int m = 1; m <= 8; m <<= 1) {
#pragma unroll
        for (int r = 0; r < 4; ++r) p[r] += __shfl_xor(p[r], m);
    }
    if (cslot == 0) {
        float b = bh2[0];
#pragma unroll
        for (int r = 0; r < 4; ++r) {
            int n = n0 + jgrp * 4 + r;
            if (n < N) out[n] = p[r] + b;
        }
    }
}

// ---------------------------------------------------------------------------
extern "C" void kernel_launch(void* const* d_in, const int* in_sizes, int n_in,
                              void* d_out, int out_size, void* d_ws, size_t ws_size,
                              hipStream_t stream) {
    const float* x    = (const float*)d_in[0];
    const int*   ei   = (const int*)d_in[1];
    const float* ea   = (const float*)d_in[2];
    const float* Wl1  = (const float*)d_in[3];
    const float* bl1  = (const float*)d_in[4];
    const float* Wr1  = (const float*)d_in[5];
    const float* br1  = (const float*)d_in[6];
    const float* We1  = (const float*)d_in[7];
    const float* att1 = (const float*)d_in[8];
    const float* bias1= (const float*)d_in[9];
    const float* Wl2  = (const float*)d_in[10];
    const float* bl2  = (const float*)d_in[11];
    const float* Wr2  = (const float*)d_in[12];
    const float* br2  = (const float*)d_in[13];
    const float* We2  = (const float*)d_in[14];
    const float* att2 = (const float*)d_in[15];
    const float* bias2= (const float*)d_in[16];
    const float* Wh1  = (const float*)d_in[17];
    const float* bh1  = (const float*)d_in[18];
    const float* Wh2  = (const float*)d_in[19];
    const float* bh2  = (const float*)d_in[20];

    int N = in_sizes[0] / 6;
    int E = in_sizes[1] / 2;
    const int* srcv = ei;
    const int* dstv = ei + E;

    int NB = (N + NB_NODES - 1) >> NB_SHIFT;
    int EPB = (E + NBLK_PART - 1) / NBLK_PART;

    char* w = (char*)d_ws;
    auto align256 = [](size_t v) { return (v + 255) & ~(size_t)255; };
    _Float16* xlh = (_Float16*)w;
    char* ip = w + align256((size_t)N * 128 * 2);
    _Float16* xrh = (_Float16*)ip; ip += align256((size_t)N * 128 * 2);
    _Float16* h1h = (_Float16*)ip; ip += align256((size_t)N * 128 * 2);
    _Float16* xl2h = (_Float16*)ip; ip += align256((size_t)N * 64 * 2);
    _Float16* xr2h = (_Float16*)ip; ip += align256((size_t)N * 64 * 2);
    int* off = (int*)ip;  ip += align256((size_t)(N + 1) * 4);
    int4* rng = (int4*)ip; ip += align256((size_t)N * 16);
    int* Mbuf = (int*)ip; ip += align256((size_t)NB * NBLK_PART * 4);
    int* btot = (int*)ip; ip += align256((size_t)NB * 4);
    int2* csr_edge = (int2*)ip;

    // ebuf aliases h1h (dead until c1 writes it): E*8 = 12.8MB <= 25.6MB.
    int2* ebuf = (int2*)h1h;
    float* h2 = (float*)xlh;   // h2 aliases xlh (dead after c1)

    int prep_blocks = (int)(((size_t)N * 64 + 255) / 256);
    if (prep_blocks < NBLK_PART) prep_blocks = NBLK_PART;
    prepA_kernel<<<prep_blocks, 256, 0, stream>>>(
        x, Wl1, bl1, Wr1, br1, xlh, xrh, N, dstv, Mbuf, E, EPB, NB);
    partB1_scanrow<<<NB, 256, 0, stream>>>(Mbuf, btot);
    partC_scatter<<<NBLK_PART, 256, 0, stream>>>(
        srcv, dstv, (const float2*)ea, Mbuf, btot, ebuf, E, EPB, NB);
    partD_finalize<<<NB, 256, 0, stream>>>(ebuf, btot, off, csr_edge, rng, N, NB, E);

    size_t nwv = (size_t)((N + 1) / 2);
    c1_kernel<<<(nwv * 64 + 255) / 256, 256, 0, stream>>>(
        off, csr_edge, xlh, xrh, We1, att1, bias1, h1h, N);
    a2_kernel<<<(N + 63) / 64, 256, 0, stream>>>(
        h1h, Wl2, bl2, Wr2, br2, xl2h, xr2h, N);
    c2_kernel<<<(nwv * 64 + 255) / 256, 256, 0, stream>>>(
        rng, csr_edge, xl2h, xr2h, We2, att2, bias2, h2, N);
    head_kernel<<<(N + 63) / 64, 256, 0, stream>>>(
        h2, Wh1, bh1, Wh2, bh2, (float*)d_out, N);
}